// Round 3
// baseline (82.069 us; speedup 1.0000x reference)
//
#include <hip/hip_runtime.h>

#define N_LEAVES  256
#define N_CLASSES 512
#define ROWS_PER_WAVE 4

typedef float f32x4 __attribute__((ext_vector_type(4)));

// One 64-lane wave per ROWS_PER_WAVE batch rows, phase-batched for MLP:
//   phase 1: issue 4 independent weight-row loads (f32x4/lane, nontemporal)
//   phase 2: 4 lane-local argmaxes, then interleaved 6-step shfl_xor
//            butterflies (first-occurrence tie-break like jnp.argmax)
//   phase 3: issue 8 independent gather loads from opinions (L2-resident)
//   phase 4: 8 nontemporal stores (2 KiB contiguous per row)
__global__ __launch_bounds__(256) void OutputLayer_41961830482215_kernel(
    const float* __restrict__ opinions,
    const float* __restrict__ weights,
    float* __restrict__ out,
    int batch)
{
    const int wave = threadIdx.x >> 6;   // 0..3
    const int lane = threadIdx.x & 63;
    const long long row0 =
        ((long long)blockIdx.x * 4 + wave) * ROWS_PER_WAVE;

    // ---- phase 1: weight loads (independent, in flight together) ----
    f32x4 w[ROWS_PER_WAVE];
    bool valid[ROWS_PER_WAVE];
    #pragma unroll
    for (int r = 0; r < ROWS_PER_WAVE; ++r) {
        const long long row = row0 + r;
        valid[r] = row < batch;
        if (valid[r]) {
            w[r] = __builtin_nontemporal_load(
                reinterpret_cast<const f32x4*>(weights + row * N_LEAVES) + lane);
        }
    }

    // ---- phase 2: argmax per row ----
    float best[ROWS_PER_WAVE];
    int   bidx[ROWS_PER_WAVE];
    #pragma unroll
    for (int r = 0; r < ROWS_PER_WAVE; ++r) {
        best[r] = w[r].x;
        bidx[r] = lane * 4;
        if (w[r].y > best[r]) { best[r] = w[r].y; bidx[r] = lane * 4 + 1; }
        if (w[r].z > best[r]) { best[r] = w[r].z; bidx[r] = lane * 4 + 2; }
        if (w[r].w > best[r]) { best[r] = w[r].w; bidx[r] = lane * 4 + 3; }
    }
    // interleaved butterflies: the 4 rows' shuffle chains pipeline
    #pragma unroll
    for (int off = 32; off >= 1; off >>= 1) {
        float ov[ROWS_PER_WAVE];
        int   oi[ROWS_PER_WAVE];
        #pragma unroll
        for (int r = 0; r < ROWS_PER_WAVE; ++r) {
            ov[r] = __shfl_xor(best[r], off);
            oi[r] = __shfl_xor(bidx[r], off);
        }
        #pragma unroll
        for (int r = 0; r < ROWS_PER_WAVE; ++r) {
            if (ov[r] > best[r] || (ov[r] == best[r] && oi[r] < bidx[r])) {
                best[r] = ov[r]; bidx[r] = oi[r];
            }
        }
    }

    // ---- phase 3: gather loads (8 independent f32x4 loads) ----
    f32x4 lo[ROWS_PER_WAVE], hi[ROWS_PER_WAVE];
    #pragma unroll
    for (int r = 0; r < ROWS_PER_WAVE; ++r) {
        if (valid[r]) {
            const f32x4* __restrict__ src = reinterpret_cast<const f32x4*>(
                opinions + (long long)bidx[r] * N_CLASSES);
            lo[r] = src[lane];
            hi[r] = src[lane + 64];
        }
    }

    // ---- phase 4: stores (nontemporal, full-line, contiguous per row) ----
    #pragma unroll
    for (int r = 0; r < ROWS_PER_WAVE; ++r) {
        if (valid[r]) {
            f32x4* dst =
                reinterpret_cast<f32x4*>(out + (row0 + r) * N_CLASSES);
            __builtin_nontemporal_store(lo[r], dst + lane);
            __builtin_nontemporal_store(hi[r], dst + lane + 64);
        }
    }
}

extern "C" void kernel_launch(void* const* d_in, const int* in_sizes, int n_in,
                              void* d_out, int out_size, void* d_ws, size_t ws_size,
                              hipStream_t stream) {
    const float* opinions = (const float*)d_in[0];   // [256, 512]
    const float* weights  = (const float*)d_in[1];   // [batch, 256]
    float* out = (float*)d_out;                      // [batch, 512]
    const int batch = in_sizes[1] / N_LEAVES;
    const int rows_per_block = 4 * ROWS_PER_WAVE;    // 4 waves x 4 rows
    const int blocks = (batch + rows_per_block - 1) / rows_per_block;
    OutputLayer_41961830482215_kernel<<<blocks, 256, 0, stream>>>(
        opinions, weights, out, batch);
}